// Round 5
// baseline (232.008 us; speedup 1.0000x reference)
//
#include <hip/hip_runtime.h>
#include <hip/hip_bf16.h>
#include <stdint.h>

#define N_TOK 8192
#define D 128
#define QTILES (N_TOK / 16)  // 512
#define KVB 64               // kv rows per staged tile
#define KVTILES (N_TOK / KVB)  // 128

typedef __attribute__((ext_vector_type(8))) short short8;      // bf16x8 frag
typedef __attribute__((ext_vector_type(4))) short short4v;     // 4 bf16 (8B)
typedef __attribute__((ext_vector_type(4))) float f32x4;       // MFMA accum
typedef __attribute__((ext_vector_type(8))) _Float16 half8;    // f16x8 frag
typedef __attribute__((ext_vector_type(4))) _Float16 half4;    // 4 f16 (8B)

__device__ __forceinline__ ushort f2bf(float f) {
    union { float f; uint32_t u; } cv; cv.f = f;
    uint32_t u = cv.u;
    return (ushort)((u + 0x7fffu + ((u >> 16) & 1u)) >> 16);  // RNE
}
__device__ __forceinline__ float bf2f(ushort h) {
    union { uint32_t u; float f; } cv; cv.u = ((uint32_t)h) << 16;
    return cv.f;
}
__device__ __forceinline__ f32x4 zero4() {
    f32x4 z; z[0] = 0.f; z[1] = 0.f; z[2] = 0.f; z[3] = 0.f; return z;
}

// -------- kernel 1: f32 -> double-bf16 split (X and the 3 weights) ----------
__global__ void cvt_kernel(const float* __restrict__ X, const float* __restrict__ Wq,
                           const float* __restrict__ Wk, const float* __restrict__ Wv,
                           ushort* __restrict__ Xhi, ushort* __restrict__ Xlo,
                           ushort* __restrict__ Whi, ushort* __restrict__ Wlo, int nX) {
    int i = blockIdx.x * blockDim.x + threadIdx.x;
    int e = i * 4;
    int total = nX + 3 * 16384;
    if (e >= total) return;
    const float* src; ushort* dhi; ushort* dlo; int off;
    if (e < nX) { src = X; dhi = Xhi; dlo = Xlo; off = e; }
    else {
        int w = e - nX;
        int m = w >> 14;
        off = w & 16383;
        src = (m == 0) ? Wq : ((m == 1) ? Wk : Wv);
        dhi = Whi + (m << 14);
        dlo = Wlo + (m << 14);
    }
    f32x4 v = *(const f32x4*)(src + off);
    short4v ph, pl;
    #pragma unroll
    for (int r = 0; r < 4; ++r) {
        ushort h = f2bf(v[r]);
        ph[r] = (short)h;
        pl[r] = (short)f2bf(v[r] - bf2f(h));
    }
    *(short4v*)(dhi + off) = ph;
    *(short4v*)(dlo + off) = pl;
}

// -------- kernel 2: projections via MFMA (double-bf16 inputs) ---------------
// Q^T = Wq * X^T, K^T = Wk * X^T computed in f32 via 3-term bf16, then stored
// as SINGLE f16 (Q,K f16 rounding is the only QK^T-path error source).
// V single bf16, stored transposed Vt[128][N].
__global__ __launch_bounds__(64) void proj_kernel(
    const ushort* __restrict__ Xhi, const ushort* __restrict__ Xlo,
    const ushort* __restrict__ Whi, const ushort* __restrict__ Wlo,
    ushort* __restrict__ Qh, ushort* __restrict__ Kh, ushort* __restrict__ Vt) {
    const int lane = threadIdx.x & 63;
    const int g = lane >> 4, r16 = lane & 15;
    const int nbase = blockIdx.x * 16;

    short8 xh[4], xl[4];
    const ushort* xrh = Xhi + (size_t)(nbase + r16) * D + 8 * g;
    const ushort* xrl = Xlo + (size_t)(nbase + r16) * D + 8 * g;
    #pragma unroll
    for (int ds = 0; ds < 4; ++ds) {
        xh[ds] = *(const short8*)(xrh + 32 * ds);
        xl[ds] = *(const short8*)(xrl + 32 * ds);
    }

    #pragma unroll
    for (int m = 0; m < 2; ++m) {
        const ushort* Wh = Whi + m * 16384;
        const ushort* Wl = Wlo + m * 16384;
        ushort* O = m ? Kh : Qh;
        #pragma unroll
        for (int jt = 0; jt < 8; ++jt) {
            f32x4 acc = zero4();
            const ushort* wrh = Wh + (size_t)(16 * jt + r16) * D + 8 * g;
            const ushort* wrl = Wl + (size_t)(16 * jt + r16) * D + 8 * g;
            #pragma unroll
            for (int ds = 0; ds < 4; ++ds) {
                short8 wh = *(const short8*)(wrh + 32 * ds);
                short8 wl = *(const short8*)(wrl + 32 * ds);
                acc = __builtin_amdgcn_mfma_f32_16x16x32_bf16(wh, xh[ds], acc, 0, 0, 0);
                acc = __builtin_amdgcn_mfma_f32_16x16x32_bf16(wh, xl[ds], acc, 0, 0, 0);
                acc = __builtin_amdgcn_mfma_f32_16x16x32_bf16(wl, xh[ds], acc, 0, 0, 0);
            }
            half4 pk;
            #pragma unroll
            for (int r = 0; r < 4; ++r) pk[r] = (_Float16)acc[r];
            // lane holds rows j=16jt+4g+r, col n=nbase+r16
            *(half4*)(O + (size_t)(nbase + r16) * D + 16 * jt + 4 * g) = pk;
        }
    }
    {
        const ushort* Wh = Whi + 32768;
        const ushort* Wl = Wlo + 32768;
        #pragma unroll
        for (int jt = 0; jt < 8; ++jt) {
            f32x4 acc = zero4();
            const ushort* wrh = Wh + (size_t)(16 * jt + r16) * D + 8 * g;
            const ushort* wrl = Wl + (size_t)(16 * jt + r16) * D + 8 * g;
            #pragma unroll
            for (int ds = 0; ds < 4; ++ds) {
                short8 wh = *(const short8*)(wrh + 32 * ds);
                short8 wl = *(const short8*)(wrl + 32 * ds);
                acc = __builtin_amdgcn_mfma_f32_16x16x32_bf16(xh[ds], wh, acc, 0, 0, 0);
                acc = __builtin_amdgcn_mfma_f32_16x16x32_bf16(xl[ds], wh, acc, 0, 0, 0);
                acc = __builtin_amdgcn_mfma_f32_16x16x32_bf16(xh[ds], wl, acc, 0, 0, 0);
            }
            short4v pk;
            #pragma unroll
            for (int r = 0; r < 4; ++r) pk[r] = (short)f2bf(acc[r]);
            *(short4v*)(Vt + (size_t)(16 * jt + r16) * N_TOK + nbase + 4 * g) = pk;
        }
    }
}

// -------- kernel 3: flash attention, LDS-staged, f16 QK^T, 48KB LDS ---------
// 4 waves/block, 32 q-rows each. K (f16, hi-only) + Vt slice staged to LDS.
// S^T = Kh*Qh^T (1 f16 MFMA term) -> q = lane&15 lane-local softmax.
// O^T = V^T*P^T (bf16) -> lane-local rescale; bf16 partial epilogue.
template<int NS>
__global__ __launch_bounds__(256, 3) void flash_kernel(
    const ushort* __restrict__ Qh, const ushort* __restrict__ Kh,
    const ushort* __restrict__ Vt, ushort* __restrict__ Opb, float* __restrict__ ML) {
    __shared__ __align__(16) ushort K_lds[KVB * D];    // 16 KB f16, swizzled
    __shared__ __align__(16) ushort V_lds[D * KVB];    // 16 KB bf16, swizzled
    __shared__ __align__(16) ushort P_lds[4 * 2048];   // 4 KB per wave

    const int tid = threadIdx.x;
    const int lane = tid & 63;
    const int wid = tid >> 6;
    const int g = lane >> 4, r16 = lane & 15;
    const int sp = blockIdx.x % NS;
    const int qg = blockIdx.x / NS;
    const int t0 = (KVTILES * sp) / NS;       // uneven split by 64-row tiles
    const int t1 = (KVTILES * (sp + 1)) / NS;
    const int qbase = qg * 128 + wid * 32;

    // ---- hoist Q fragments (2 subtiles x 4 d-slices, f16)
    half8 qf[2][4];
    #pragma unroll
    for (int qa = 0; qa < 2; ++qa) {
        const ushort* qr = Qh + (size_t)(qbase + 16 * qa + r16) * D + 8 * g;
        #pragma unroll
        for (int ds = 0; ds < 4; ++ds)
            qf[qa][ds] = *(const half8*)(qr + 32 * ds);
    }

    float m[2] = {-INFINITY, -INFINITY}, l[2] = {0.f, 0.f};
    f32x4 o[2][8];
    #pragma unroll
    for (int qa = 0; qa < 2; ++qa)
        #pragma unroll
        for (int dt = 0; dt < 8; ++dt) o[qa][dt] = zero4();

    ushort* P_w = &P_lds[wid * 2048];

    for (int it = t0; it < t1; ++it) {
        const int kv = it * KVB;
        // ---- stage: issue all 8 global loads, then 8 LDS writes
        short8 sk[4], sv[4];
        #pragma unroll
        for (int rr = 0; rr < 4; ++rr) {
            int idx = tid + 256 * rr;              // [0,1024)
            int row = idx >> 4, seg = idx & 15;
            sk[rr] = *(const short8*)(Kh + (size_t)(kv + row) * D + seg * 8);
        }
        #pragma unroll
        for (int rr = 0; rr < 4; ++rr) {
            int idx = tid + 256 * rr;              // [0,1024)
            int row = idx >> 3, seg = idx & 7;
            sv[rr] = *(const short8*)(Vt + (size_t)row * N_TOK + kv + seg * 8);
        }
        __syncthreads();   // previous compute done before overwriting LDS
        #pragma unroll
        for (int rr = 0; rr < 4; ++rr) {
            int idx = tid + 256 * rr;
            int row = idx >> 4, seg = idx & 15;
            *(short8*)&K_lds[(row * 128 + seg * 8) ^ ((row & 7) << 3)] = sk[rr];
        }
        #pragma unroll
        for (int rr = 0; rr < 4; ++rr) {
            int idx = tid + 256 * rr;
            int row = idx >> 3, seg = idx & 7;
            *(short8*)&V_lds[(row * 64 + seg * 8) ^ ((row & 7) << 3)] = sv[rr];
        }
        __syncthreads();

        // ---- S^T = K*Q^T : 4 kv-subtiles x 4 d-slices x 2 qa (f16, 1 term)
        f32x4 s[2][4];
        #pragma unroll
        for (int qa = 0; qa < 2; ++qa)
            #pragma unroll
            for (int t = 0; t < 4; ++t) s[qa][t] = zero4();
        __builtin_amdgcn_s_setprio(1);
        #pragma unroll
        for (int t = 0; t < 4; ++t) {
            #pragma unroll
            for (int ds = 0; ds < 4; ++ds) {
                int row = 16 * t + r16;
                half8 kf = *(const half8*)&K_lds[(row * 128 + 32 * ds + 8 * g) ^ ((row & 7) << 3)];
                #pragma unroll
                for (int qa = 0; qa < 2; ++qa)
                    s[qa][t] = __builtin_amdgcn_mfma_f32_16x16x32_f16(kf, qf[qa][ds], s[qa][t], 0, 0, 0);
            }
        }
        __builtin_amdgcn_s_setprio(0);
        // ---- online softmax per q-subtile (lane-local per r16)
        #pragma unroll
        for (int qa = 0; qa < 2; ++qa) {
            float tm = -INFINITY;
            #pragma unroll
            for (int t = 0; t < 4; ++t)
                #pragma unroll
                for (int r = 0; r < 4; ++r) tm = fmaxf(tm, s[qa][t][r]);
            tm = fmaxf(tm, __shfl_xor(tm, 16));
            tm = fmaxf(tm, __shfl_xor(tm, 32));
            float mnew = fmaxf(m[qa], tm);
            float scale = __expf(m[qa] - mnew);
            float psum = 0.f;
            #pragma unroll
            for (int t = 0; t < 4; ++t) {
                short4v pk;
                #pragma unroll
                for (int r = 0; r < 4; ++r) {
                    float p = __expf(s[qa][t][r] - mnew);
                    psum += p;
                    pk[r] = (short)f2bf(p);
                }
                *(short4v*)&P_w[(qa * 1024 + r16 * 64 + 16 * t + 4 * g) ^ ((r16 & 7) << 3)] = pk;
            }
            psum += __shfl_xor(psum, 16);
            psum += __shfl_xor(psum, 32);
            l[qa] = l[qa] * scale + psum;
            m[qa] = mnew;
            #pragma unroll
            for (int dt = 0; dt < 8; ++dt) o[qa][dt] *= scale;
        }
        // ---- O^T += V^T * P^T : 2 kv-chunks x 8 d-tiles, V frag shared by qa
        __builtin_amdgcn_s_setprio(1);
        #pragma unroll
        for (int c = 0; c < 2; ++c) {
            short8 pf0 = *(const short8*)&P_w[(r16 * 64 + 32 * c + 8 * g) ^ ((r16 & 7) << 3)];
            short8 pf1 = *(const short8*)&P_w[(1024 + r16 * 64 + 32 * c + 8 * g) ^ ((r16 & 7) << 3)];
            #pragma unroll
            for (int dt = 0; dt < 8; ++dt) {
                int row = 16 * dt + r16;
                short8 vf = *(const short8*)&V_lds[(row * 64 + 32 * c + 8 * g) ^ ((row & 7) << 3)];
                o[0][dt] = __builtin_amdgcn_mfma_f32_16x16x32_bf16(vf, pf0, o[0][dt], 0, 0, 0);
                o[1][dt] = __builtin_amdgcn_mfma_f32_16x16x32_bf16(vf, pf1, o[1][dt], 0, 0, 0);
            }
        }
        __builtin_amdgcn_s_setprio(0);
    }
    // ---- epilogue: partial O (pre-division, bf16) + (m, l)
    #pragma unroll
    for (int qa = 0; qa < 2; ++qa) {
        ushort* obase = Opb + ((size_t)sp * N_TOK + qbase + 16 * qa + r16) * D + 4 * g;
        #pragma unroll
        for (int dt = 0; dt < 8; ++dt) {
            short4v pk;
            #pragma unroll
            for (int r = 0; r < 4; ++r) pk[r] = (short)f2bf(o[qa][dt][r]);
            *(short4v*)(obase + 16 * dt) = pk;
        }
        if (g == 0) {
            int qt = (qbase + 16 * qa) >> 4;
            float* ml = ML + ((size_t)sp * QTILES + qt) * 32;
            ml[r16] = m[qa];
            ml[16 + r16] = l[qa];
        }
    }
}

// -------- kernel 4: merge the NS KV-split partials (bf16 partials) ----------
template<int NS>
__global__ void merge_kernel(const ushort* __restrict__ Opb, const float* __restrict__ ML,
                             float* __restrict__ out) {
    int i = blockIdx.x * blockDim.x + threadIdx.x;
    int e = i * 4;
    if (e >= N_TOK * D) return;
    int q = e >> 7;
    int qt = q >> 4, qr = q & 15;
    float mv[NS], lv[NS];
    float M = -INFINITY;
    #pragma unroll
    for (int s = 0; s < NS; ++s) {
        const float* ml = ML + ((size_t)s * QTILES + qt) * 32;
        mv[s] = ml[qr];
        lv[s] = ml[16 + qr];
        M = fmaxf(M, mv[s]);
    }
    float L = 0.f, a[NS];
    #pragma unroll
    for (int s = 0; s < NS; ++s) { a[s] = __expf(mv[s] - M); L += a[s] * lv[s]; }
    float inv = 1.f / L;
    f32x4 acc = zero4();
    #pragma unroll
    for (int s = 0; s < NS; ++s) {
        short4v ov = *(const short4v*)(Opb + (size_t)s * N_TOK * D + e);
        #pragma unroll
        for (int r = 0; r < 4; ++r) acc[r] += bf2f((ushort)ov[r]) * a[s];
    }
    *(f32x4*)(out + e) = acc * inv;
}

extern "C" void kernel_launch(void* const* d_in, const int* in_sizes, int n_in,
                              void* d_out, int out_size, void* d_ws, size_t ws_size,
                              hipStream_t stream) {
    const float* X  = (const float*)d_in[0];
    const float* Wq = (const float*)d_in[1];
    const float* Wk = (const float*)d_in[2];
    const float* Wv = (const float*)d_in[3];
    float* out = (float*)d_out;

    char* ws = (char*)d_ws;
    ushort* Xhi = (ushort*)(ws);                   // 2 MB
    ushort* Xlo = (ushort*)(ws + 2097152);         // 2 MB
    ushort* Whi = (ushort*)(ws + 4194304);         // 96 KB
    ushort* Wlo = (ushort*)(ws + 4292608);         // 96 KB
    ushort* Qh  = (ushort*)(ws + 4390912);         // 2 MB (f16)
    ushort* Kh  = (ushort*)(ws + 6488064);         // 2 MB (f16)
    ushort* Vt  = (ushort*)(ws + 8585216);         // 2 MB (bf16, transposed)
    ushort* Opb = (ushort*)(ws + 10682368);        // NS * 2 MB (bf16 partials)

    const size_t op_off = 10682368;
    const size_t need12 = op_off + (size_t)12 * N_TOK * D * 2 + (size_t)12 * QTILES * 32 * 4;
    const size_t need8  = op_off + (size_t)8  * N_TOK * D * 2 + (size_t)8  * QTILES * 32 * 4;

    int nX = N_TOK * D;
    int total4 = (nX + 3 * 16384) / 4;
    cvt_kernel<<<(total4 + 255) / 256, 256, 0, stream>>>(X, Wq, Wk, Wv, Xhi, Xlo, Whi, Wlo, nX);
    proj_kernel<<<QTILES, 64, 0, stream>>>(Xhi, Xlo, Whi, Wlo, Qh, Kh, Vt);

    if (ws_size >= need12) {
        float* ML = (float*)(ws + op_off + (size_t)12 * N_TOK * D * 2);
        flash_kernel<12><<<(N_TOK / 128) * 12, 256, 0, stream>>>(Qh, Kh, Vt, Opb, ML);
        merge_kernel<12><<<(N_TOK * D / 4 + 255) / 256, 256, 0, stream>>>(Opb, ML, out);
    } else if (ws_size >= need8) {
        float* ML = (float*)(ws + op_off + (size_t)8 * N_TOK * D * 2);
        flash_kernel<8><<<(N_TOK / 128) * 8, 256, 0, stream>>>(Qh, Kh, Vt, Opb, ML);
        merge_kernel<8><<<(N_TOK * D / 4 + 255) / 256, 256, 0, stream>>>(Opb, ML, out);
    } else {
        float* ML = (float*)(ws + op_off + (size_t)4 * N_TOK * D * 2);
        flash_kernel<4><<<(N_TOK / 128) * 4, 256, 0, stream>>>(Qh, Kh, Vt, Opb, ML);
        merge_kernel<4><<<(N_TOK * D / 4 + 255) / 256, 256, 0, stream>>>(Opb, ML, out);
    }
}

// Round 6
// 80.784 us; speedup vs baseline: 2.8720x; 2.8720x over previous
//
#include <hip/hip_runtime.h>
#include <hip/hip_bf16.h>
#include <stdint.h>

#define N_TOK 8192
#define D 128
#define QTILES (N_TOK / 16)    // 512
#define KVB 64                 // kv rows per staged tile
#define KVTILES (N_TOK / KVB)  // 128

typedef __attribute__((ext_vector_type(8))) short short8;      // bf16x8 frag
typedef __attribute__((ext_vector_type(4))) short short4v;     // 4 bf16 (8B)
typedef __attribute__((ext_vector_type(4))) float f32x4;       // MFMA accum
typedef __attribute__((ext_vector_type(8))) _Float16 half8;    // f16x8 frag
typedef __attribute__((ext_vector_type(4))) _Float16 half4;    // 4 f16 (8B)

__device__ __forceinline__ ushort f2bf(float f) {
    union { float f; uint32_t u; } cv; cv.f = f;
    uint32_t u = cv.u;
    return (ushort)((u + 0x7fffu + ((u >> 16) & 1u)) >> 16);  // RNE
}
__device__ __forceinline__ float bf2f(ushort h) {
    union { uint32_t u; float f; } cv; cv.u = ((uint32_t)h) << 16;
    return cv.f;
}
__device__ __forceinline__ f32x4 zero4() {
    f32x4 z; z[0] = 0.f; z[1] = 0.f; z[2] = 0.f; z[3] = 0.f; return z;
}

// -------- kernel 1: f32 -> double-bf16 split (X and the 3 weights) ----------
__global__ void cvt_kernel(const float* __restrict__ X, const float* __restrict__ Wq,
                           const float* __restrict__ Wk, const float* __restrict__ Wv,
                           ushort* __restrict__ Xhi, ushort* __restrict__ Xlo,
                           ushort* __restrict__ Whi, ushort* __restrict__ Wlo, int nX) {
    int i = blockIdx.x * blockDim.x + threadIdx.x;
    int e = i * 4;
    int total = nX + 3 * 16384;
    if (e >= total) return;
    const float* src; ushort* dhi; ushort* dlo; int off;
    if (e < nX) { src = X; dhi = Xhi; dlo = Xlo; off = e; }
    else {
        int w = e - nX;
        int m = w >> 14;
        off = w & 16383;
        src = (m == 0) ? Wq : ((m == 1) ? Wk : Wv);
        dhi = Whi + (m << 14);
        dlo = Wlo + (m << 14);
    }
    f32x4 v = *(const f32x4*)(src + off);
    short4v ph, pl;
    #pragma unroll
    for (int r = 0; r < 4; ++r) {
        ushort h = f2bf(v[r]);
        ph[r] = (short)h;
        pl[r] = (short)f2bf(v[r] - bf2f(h));
    }
    *(short4v*)(dhi + off) = ph;
    *(short4v*)(dlo + off) = pl;
}

// -------- kernel 2: projections via MFMA (double-bf16 in, f16/bf16 out) -----
// 4 waves per block; wave w handles jt in {2w, 2w+1} for Q, K, V.
// Q^T/K^T computed in f32 via 3-term bf16, stored single f16.
// V single bf16, stored transposed Vt[128][N].
__global__ __launch_bounds__(256) void proj_kernel(
    const ushort* __restrict__ Xhi, const ushort* __restrict__ Xlo,
    const ushort* __restrict__ Whi, const ushort* __restrict__ Wlo,
    ushort* __restrict__ Qh, ushort* __restrict__ Kh, ushort* __restrict__ Vt) {
    const int tid = threadIdx.x;
    const int lane = tid & 63;
    const int wid = tid >> 6;
    const int g = lane >> 4, r16 = lane & 15;
    const int nbase = blockIdx.x * 16;

    short8 xh[4], xl[4];
    const ushort* xrh = Xhi + (size_t)(nbase + r16) * D + 8 * g;
    const ushort* xrl = Xlo + (size_t)(nbase + r16) * D + 8 * g;
    #pragma unroll
    for (int ds = 0; ds < 4; ++ds) {
        xh[ds] = *(const short8*)(xrh + 32 * ds);
        xl[ds] = *(const short8*)(xrl + 32 * ds);
    }

    #pragma unroll
    for (int m = 0; m < 2; ++m) {
        const ushort* Wh = Whi + m * 16384;
        const ushort* Wl = Wlo + m * 16384;
        ushort* O = m ? Kh : Qh;
        #pragma unroll
        for (int jj = 0; jj < 2; ++jj) {
            int jt = 2 * wid + jj;
            f32x4 acc = zero4();
            const ushort* wrh = Wh + (size_t)(16 * jt + r16) * D + 8 * g;
            const ushort* wrl = Wl + (size_t)(16 * jt + r16) * D + 8 * g;
            #pragma unroll
            for (int ds = 0; ds < 4; ++ds) {
                short8 wh = *(const short8*)(wrh + 32 * ds);
                short8 wl = *(const short8*)(wrl + 32 * ds);
                acc = __builtin_amdgcn_mfma_f32_16x16x32_bf16(wh, xh[ds], acc, 0, 0, 0);
                acc = __builtin_amdgcn_mfma_f32_16x16x32_bf16(wh, xl[ds], acc, 0, 0, 0);
                acc = __builtin_amdgcn_mfma_f32_16x16x32_bf16(wl, xh[ds], acc, 0, 0, 0);
            }
            half4 pk;
            #pragma unroll
            for (int r = 0; r < 4; ++r) pk[r] = (_Float16)acc[r];
            *(half4*)(O + (size_t)(nbase + r16) * D + 16 * jt + 4 * g) = pk;
        }
    }
    {
        const ushort* Wh = Whi + 32768;
        const ushort* Wl = Wlo + 32768;
        #pragma unroll
        for (int jj = 0; jj < 2; ++jj) {
            int jt = 2 * wid + jj;
            f32x4 acc = zero4();
            const ushort* wrh = Wh + (size_t)(16 * jt + r16) * D + 8 * g;
            const ushort* wrl = Wl + (size_t)(16 * jt + r16) * D + 8 * g;
            #pragma unroll
            for (int ds = 0; ds < 4; ++ds) {
                short8 wh = *(const short8*)(wrh + 32 * ds);
                short8 wl = *(const short8*)(wrl + 32 * ds);
                acc = __builtin_amdgcn_mfma_f32_16x16x32_bf16(xh[ds], wh, acc, 0, 0, 0);
                acc = __builtin_amdgcn_mfma_f32_16x16x32_bf16(xl[ds], wh, acc, 0, 0, 0);
                acc = __builtin_amdgcn_mfma_f32_16x16x32_bf16(xh[ds], wl, acc, 0, 0, 0);
            }
            short4v pk;
            #pragma unroll
            for (int r = 0; r < 4; ++r) pk[r] = (short)f2bf(acc[r]);
            *(short4v*)(Vt + (size_t)(16 * jt + r16) * N_TOK + nbase + 4 * g) = pk;
        }
    }
}

// -------- kernel 3: flash attention, double-buffered LDS pipeline -----------
// 4 waves/block, 32 q-rows each. NS=8 -> sp == XCD id (L2-affine K/V).
// Pipeline per iter: issue loads(it+1) -> compute(buf) -> ds_write(buf^1)
// -> ONE barrier. Global latency hides under QK+softmax+PV.
template<int NS>
__global__ __launch_bounds__(256, 2) void flash_kernel(
    const ushort* __restrict__ Qh, const ushort* __restrict__ Kh,
    const ushort* __restrict__ Vt, ushort* __restrict__ Opb, float* __restrict__ ML) {
    __shared__ __align__(16) ushort K_lds[2][KVB * D];   // 2 x 16 KB f16
    __shared__ __align__(16) ushort V_lds[2][D * KVB];   // 2 x 16 KB bf16
    __shared__ __align__(16) ushort P_lds[4 * 2048];     // 16 KB

    const int tid = threadIdx.x;
    const int lane = tid & 63;
    const int wid = tid >> 6;
    const int g = lane >> 4, r16 = lane & 15;
    const int sp = blockIdx.x % NS;        // == XCD id when NS==8
    const int qg = blockIdx.x / NS;
    const int t0 = (KVTILES * sp) / NS;
    const int t1 = (KVTILES * (sp + 1)) / NS;
    const int qbase = qg * 128 + wid * 32;
    const int pswz = (r16 & 7) << 3;

    // ---- hoist Q fragments (2 subtiles x 4 d-slices, f16)
    half8 qf[2][4];
    #pragma unroll
    for (int qa = 0; qa < 2; ++qa) {
        const ushort* qr = Qh + (size_t)(qbase + 16 * qa + r16) * D + 8 * g;
        #pragma unroll
        for (int ds = 0; ds < 4; ++ds)
            qf[qa][ds] = *(const half8*)(qr + 32 * ds);
    }

    float m[2] = {-INFINITY, -INFINITY}, l[2] = {0.f, 0.f};
    f32x4 o[2][8];
    #pragma unroll
    for (int qa = 0; qa < 2; ++qa)
        #pragma unroll
        for (int dt = 0; dt < 8; ++dt) o[qa][dt] = zero4();

    ushort* P_w = &P_lds[wid * 2048];

    short8 sk[4], sv[4];

    // ---- staging helpers (register round-trip, swizzled LDS writes)
    auto LOADT = [&](int it) {
        const int kv = it * KVB;
        #pragma unroll
        for (int rr = 0; rr < 4; ++rr) {
            int idx = tid + 256 * rr;              // [0,1024)
            int row = idx >> 4, seg = idx & 15;
            sk[rr] = *(const short8*)(Kh + (size_t)(kv + row) * D + seg * 8);
        }
        #pragma unroll
        for (int rr = 0; rr < 4; ++rr) {
            int idx = tid + 256 * rr;              // [0,1024)
            int row = idx >> 3, seg = idx & 7;
            sv[rr] = *(const short8*)(Vt + (size_t)row * N_TOK + kv + seg * 8);
        }
    };
    auto WRITET = [&](int b) {
        #pragma unroll
        for (int rr = 0; rr < 4; ++rr) {
            int idx = tid + 256 * rr;
            int row = idx >> 4, seg = idx & 15;
            *(short8*)&K_lds[b][(row * 128 + seg * 8) ^ ((row & 7) << 3)] = sk[rr];
        }
        #pragma unroll
        for (int rr = 0; rr < 4; ++rr) {
            int idx = tid + 256 * rr;
            int row = idx >> 3, seg = idx & 7;
            *(short8*)&V_lds[b][(row * 64 + seg * 8) ^ ((row & 7) << 3)] = sv[rr];
        }
    };

    // ---- prologue: stage tile t0 into buffer 0
    LOADT(t0);
    WRITET(0);
    __syncthreads();

    int buf = 0;
    for (int it = t0; it < t1; ++it) {
        // issue next tile's global loads; latency hides under compute below
        if (it + 1 < t1) LOADT(it + 1);

        const ushort* kb = K_lds[buf];
        const ushort* vb = V_lds[buf];

        // ---- S^T = K*Q^T : 4 kv-subtiles x 4 d-slices x 2 qa (f16)
        f32x4 s[2][4];
        #pragma unroll
        for (int qa = 0; qa < 2; ++qa)
            #pragma unroll
            for (int t = 0; t < 4; ++t) s[qa][t] = zero4();
        __builtin_amdgcn_s_setprio(1);
        #pragma unroll
        for (int t = 0; t < 4; ++t) {
            #pragma unroll
            for (int ds = 0; ds < 4; ++ds) {
                int row = 16 * t + r16;
                half8 kf = *(const half8*)&kb[(row * 128 + 32 * ds + 8 * g) ^ ((row & 7) << 3)];
                #pragma unroll
                for (int qa = 0; qa < 2; ++qa)
                    s[qa][t] = __builtin_amdgcn_mfma_f32_16x16x32_f16(kf, qf[qa][ds], s[qa][t], 0, 0, 0);
            }
        }
        __builtin_amdgcn_s_setprio(0);

        // ---- online softmax per q-subtile (lane-local per r16)
        #pragma unroll
        for (int qa = 0; qa < 2; ++qa) {
            float tm = -INFINITY;
            #pragma unroll
            for (int t = 0; t < 4; ++t)
                #pragma unroll
                for (int r = 0; r < 4; ++r) tm = fmaxf(tm, s[qa][t][r]);
            tm = fmaxf(tm, __shfl_xor(tm, 16));
            tm = fmaxf(tm, __shfl_xor(tm, 32));
            float mnew = fmaxf(m[qa], tm);
            float scale = __expf(m[qa] - mnew);
            float psum = 0.f;
            #pragma unroll
            for (int t = 0; t < 4; ++t) {
                short4v pk;
                #pragma unroll
                for (int r = 0; r < 4; ++r) {
                    float p = __expf(s[qa][t][r] - mnew);
                    psum += p;
                    pk[r] = (short)f2bf(p);
                }
                *(short4v*)&P_w[(qa * 1024 + r16 * 64 + 16 * t + 4 * g) ^ pswz] = pk;
            }
            psum += __shfl_xor(psum, 16);
            psum += __shfl_xor(psum, 32);
            l[qa] = l[qa] * scale + psum;
            m[qa] = mnew;
            #pragma unroll
            for (int dt = 0; dt < 8; ++dt) o[qa][dt] *= scale;
        }

        // ---- O^T += V^T * P^T : 2 kv-chunks x 8 d-tiles
        __builtin_amdgcn_s_setprio(1);
        #pragma unroll
        for (int c = 0; c < 2; ++c) {
            short8 pf0 = *(const short8*)&P_w[(r16 * 64 + 32 * c + 8 * g) ^ pswz];
            short8 pf1 = *(const short8*)&P_w[(1024 + r16 * 64 + 32 * c + 8 * g) ^ pswz];
            #pragma unroll
            for (int dt = 0; dt < 8; ++dt) {
                int row = 16 * dt + r16;
                short8 vf = *(const short8*)&vb[(row * 64 + 32 * c + 8 * g) ^ ((row & 7) << 3)];
                o[0][dt] = __builtin_amdgcn_mfma_f32_16x16x32_bf16(vf, pf0, o[0][dt], 0, 0, 0);
                o[1][dt] = __builtin_amdgcn_mfma_f32_16x16x32_bf16(vf, pf1, o[1][dt], 0, 0, 0);
            }
        }
        __builtin_amdgcn_s_setprio(0);

        // ---- publish next tile into the idle buffer (vmcnt wait was hidden)
        if (it + 1 < t1) WRITET(buf ^ 1);
        __syncthreads();
        buf ^= 1;
    }

    // ---- epilogue: partial O (pre-division, bf16) + (m, l)
    #pragma unroll
    for (int qa = 0; qa < 2; ++qa) {
        ushort* obase = Opb + ((size_t)sp * N_TOK + qbase + 16 * qa + r16) * D + 4 * g;
        #pragma unroll
        for (int dt = 0; dt < 8; ++dt) {
            short4v pk;
            #pragma unroll
            for (int r = 0; r < 4; ++r) pk[r] = (short)f2bf(o[qa][dt][r]);
            *(short4v*)(obase + 16 * dt) = pk;
        }
        if (g == 0) {
            int qt = (qbase + 16 * qa) >> 4;
            float* ml = ML + ((size_t)sp * QTILES + qt) * 32;
            ml[r16] = m[qa];
            ml[16 + r16] = l[qa];
        }
    }
}

// -------- kernel 4: merge the NS KV-split partials (bf16 partials) ----------
template<int NS>
__global__ void merge_kernel(const ushort* __restrict__ Opb, const float* __restrict__ ML,
                             float* __restrict__ out) {
    int i = blockIdx.x * blockDim.x + threadIdx.x;
    int e = i * 4;
    if (e >= N_TOK * D) return;
    int q = e >> 7;
    int qt = q >> 4, qr = q & 15;
    float mv[NS], lv[NS];
    float M = -INFINITY;
    #pragma unroll
    for (int s = 0; s < NS; ++s) {
        const float* ml = ML + ((size_t)s * QTILES + qt) * 32;
        mv[s] = ml[qr];
        lv[s] = ml[16 + qr];
        M = fmaxf(M, mv[s]);
    }
    float L = 0.f, a[NS];
    #pragma unroll
    for (int s = 0; s < NS; ++s) { a[s] = __expf(mv[s] - M); L += a[s] * lv[s]; }
    float inv = 1.f / L;
    f32x4 acc = zero4();
    #pragma unroll
    for (int s = 0; s < NS; ++s) {
        short4v ov = *(const short4v*)(Opb + (size_t)s * N_TOK * D + e);
        #pragma unroll
        for (int r = 0; r < 4; ++r) acc[r] += bf2f((ushort)ov[r]) * a[s];
    }
    *(f32x4*)(out + e) = acc * inv;
}

extern "C" void kernel_launch(void* const* d_in, const int* in_sizes, int n_in,
                              void* d_out, int out_size, void* d_ws, size_t ws_size,
                              hipStream_t stream) {
    const float* X  = (const float*)d_in[0];
    const float* Wq = (const float*)d_in[1];
    const float* Wk = (const float*)d_in[2];
    const float* Wv = (const float*)d_in[3];
    float* out = (float*)d_out;

    char* ws = (char*)d_ws;
    ushort* Xhi = (ushort*)(ws);                   // 2 MB
    ushort* Xlo = (ushort*)(ws + 2097152);         // 2 MB
    ushort* Whi = (ushort*)(ws + 4194304);         // 96 KB
    ushort* Wlo = (ushort*)(ws + 4292608);         // 96 KB
    ushort* Qh  = (ushort*)(ws + 4390912);         // 2 MB (f16)
    ushort* Kh  = (ushort*)(ws + 6488064);         // 2 MB (f16)
    ushort* Vt  = (ushort*)(ws + 8585216);         // 2 MB (bf16, transposed)
    ushort* Opb = (ushort*)(ws + 10682368);        // NS * 2 MB (bf16 partials)

    const size_t op_off = 10682368;
    const size_t need8 = op_off + (size_t)8 * N_TOK * D * 2 + (size_t)8 * QTILES * 32 * 4;

    int nX = N_TOK * D;
    int total4 = (nX + 3 * 16384) / 4;
    cvt_kernel<<<(total4 + 255) / 256, 256, 0, stream>>>(X, Wq, Wk, Wv, Xhi, Xlo, Whi, Wlo, nX);
    proj_kernel<<<QTILES, 256, 0, stream>>>(Xhi, Xlo, Whi, Wlo, Qh, Kh, Vt);

    if (ws_size >= need8) {
        float* ML = (float*)(ws + op_off + (size_t)8 * N_TOK * D * 2);
        flash_kernel<8><<<(N_TOK / 128) * 8, 256, 0, stream>>>(Qh, Kh, Vt, Opb, ML);
        merge_kernel<8><<<(N_TOK * D / 4 + 255) / 256, 256, 0, stream>>>(Opb, ML, out);
    } else {
        float* ML = (float*)(ws + op_off + (size_t)4 * N_TOK * D * 2);
        flash_kernel<4><<<(N_TOK / 128) * 4, 256, 0, stream>>>(Qh, Kh, Vt, Opb, ML);
        merge_kernel<4><<<(N_TOK * D / 4 + 255) / 256, 256, 0, stream>>>(Opb, ML, out);
    }
}